// Round 1
// baseline (1277.952 us; speedup 1.0000x reference)
//
#include <hip/hip_runtime.h>
#include <hip/hip_bf16.h>

// LSTM (all-tanh gates), B=128, T=1024, IN=512, UNITS=128.
// Plan:
//   k_wt   : W [512,512] f32 -> Wt bf16 [n][k] (transposed, k-contiguous) in ws
//   k_gemm : xW = x @ W, bf16 MFMA 16x16x32, A loaded f32->cvt, out f32 (or bf16 if ws small)
//   k_scan : 128 workgroups (one per batch elem), sequential over T, U[:,j] in VGPRs

#define UNITS 128
#define IN_DIM 512
#define BATCH 128
#define SEQ 1024
#define GATES 512            // 4*UNITS
#define M_ROWS (BATCH * SEQ) // 131072

typedef __attribute__((ext_vector_type(8))) short short8;
typedef __attribute__((ext_vector_type(4))) float floatx4;

__device__ __forceinline__ unsigned short f2bf(float f) {
    unsigned int x = __builtin_bit_cast(unsigned int, f);
    unsigned int r = (x + 0x7fffu + ((x >> 16) & 1u)) >> 16; // RNE
    return (unsigned short)r;
}
__device__ __forceinline__ float bf2f(unsigned short u) {
    unsigned int x = ((unsigned int)u) << 16;
    return __builtin_bit_cast(float, x);
}
__device__ __forceinline__ unsigned int pack2(float lo, float hi) {
    return (unsigned int)f2bf(lo) | ((unsigned int)f2bf(hi) << 16);
}

// tanh(x) = 1 - 2/(exp(2x)+1); clamp so exp stays finite. ~1e-7 abs error.
__device__ __forceinline__ float fast_tanh(float x) {
    float xc = fminf(12.0f, fmaxf(-12.0f, x));
    float e = __expf(2.0f * xc);
    return 1.0f - 2.0f * __builtin_amdgcn_rcpf(e + 1.0f);
}

// ---------------- W transpose + convert: Wt[n][k] = bf16(W[k][n]) ----------
__global__ void k_wt(const float* __restrict__ W, unsigned short* __restrict__ Wt) {
    int idx = blockIdx.x * 256 + threadIdx.x; // 0..262143, coalesced writes
    int n = idx >> 9;
    int k = idx & 511;
    Wt[idx] = f2bf(W[k * 512 + n]);
}

// ---------------- GEMM: C[m][n] = sum_k A[m][k] * W[k][n] ------------------
// 128x128 block tile, BK=32, 256 threads (4 waves, 2x2 of 64x64), bf16 MFMA.
// LDS padded to 40 elems/row (+16B) -> 2-way-max bank aliasing, 16B aligned rows.
template <bool XWF32>
__global__ void __launch_bounds__(256, 2)
k_gemm(const float* __restrict__ A, const unsigned short* __restrict__ Bt,
       void* __restrict__ Cout) {
    __shared__ __align__(16) unsigned short As[128 * 40];
    __shared__ __align__(16) unsigned short Bs[128 * 40];
    const int tid = threadIdx.x;
    const int m0 = blockIdx.y << 7;
    const int n0 = blockIdx.x << 7;
    const int l = tid & 63;
    const int w = tid >> 6;
    const int wr = (w >> 1) << 6; // wave row offset within tile
    const int wc = (w & 1) << 6;  // wave col offset
    const int lrow = l & 15;      // A/B fragment: own-index = lane%16
    const int lq = l >> 4;        // k-quarter: k = lq*8 + j

    floatx4 acc[4][4] = {};

    // staging map: thread -> (row srow, 16-elem half soff)
    const int srow = tid >> 1;
    const int soff = (tid & 1) << 4;
    const float* ap = A + (size_t)(m0 + srow) * 512 + soff;
    const unsigned short* bp = Bt + (size_t)(n0 + srow) * 512 + soff;
    unsigned short* as = &As[srow * 40 + soff];
    unsigned short* bs = &Bs[srow * 40 + soff];

    for (int k0 = 0; k0 < 512; k0 += 32) {
        float4 a0 = *(const float4*)(ap + k0);
        float4 a1 = *(const float4*)(ap + k0 + 4);
        float4 a2 = *(const float4*)(ap + k0 + 8);
        float4 a3 = *(const float4*)(ap + k0 + 12);
        uint4 b0 = *(const uint4*)(bp + k0);
        uint4 b1 = *(const uint4*)(bp + k0 + 8);
        __syncthreads(); // prev iteration's readers done before overwrite
        uint4 pa0, pa1;
        pa0.x = pack2(a0.x, a0.y); pa0.y = pack2(a0.z, a0.w);
        pa0.z = pack2(a1.x, a1.y); pa0.w = pack2(a1.z, a1.w);
        pa1.x = pack2(a2.x, a2.y); pa1.y = pack2(a2.z, a2.w);
        pa1.z = pack2(a3.x, a3.y); pa1.w = pack2(a3.z, a3.w);
        *(uint4*)as = pa0;
        *(uint4*)(as + 8) = pa1;
        *(uint4*)bs = b0;
        *(uint4*)(bs + 8) = b1;
        __syncthreads();
        short8 af[4], bfv[4];
#pragma unroll
        for (int mi = 0; mi < 4; ++mi)
            af[mi] = *(const short8*)&As[(wr + mi * 16 + lrow) * 40 + lq * 8];
#pragma unroll
        for (int ni = 0; ni < 4; ++ni)
            bfv[ni] = *(const short8*)&Bs[(wc + ni * 16 + lrow) * 40 + lq * 8];
#pragma unroll
        for (int mi = 0; mi < 4; ++mi)
#pragma unroll
            for (int ni = 0; ni < 4; ++ni)
                acc[mi][ni] = __builtin_amdgcn_mfma_f32_16x16x32_bf16(
                    af[mi], bfv[ni], acc[mi][ni], 0, 0, 0);
    }
    // epilogue: C/D layout col=lane&15, row=(lane>>4)*4+r
#pragma unroll
    for (int mi = 0; mi < 4; ++mi) {
#pragma unroll
        for (int ni = 0; ni < 4; ++ni) {
            int row = m0 + wr + mi * 16 + lq * 4;
            int col = n0 + wc + ni * 16 + lrow;
            if (XWF32) {
                float* Cf = (float*)Cout;
#pragma unroll
                for (int r = 0; r < 4; ++r)
                    Cf[(size_t)(row + r) * 512 + col] = acc[mi][ni][r];
            } else {
                unsigned short* Cb = (unsigned short*)Cout;
#pragma unroll
                for (int r = 0; r < 4; ++r)
                    Cb[(size_t)(row + r) * 512 + col] = f2bf(acc[mi][ni][r]);
            }
        }
    }
}

// ---------------- recurrent scan: one workgroup per batch element ----------
// 512 threads; thread j owns gate column j with U[:,j] (128 f32) in VGPRs.
// Keras gate order i,f,g,o (chunks of 128). All-tanh variant.
template <bool XWF32>
__global__ void __launch_bounds__(512, 2)
k_scan(const void* __restrict__ xwv, const float* __restrict__ U,
       const float* __restrict__ bias, float* __restrict__ out) {
    __shared__ __align__(16) float h_lds[UNITS];
    __shared__ float g_lds[GATES];
    const int j = threadIdx.x;
    const int bb = blockIdx.x;

    float u_reg[128];
#pragma unroll
    for (int k = 0; k < 128; ++k) u_reg[k] = U[k * 512 + j];
    const float bj = bias[j];
    if (j < UNITS) h_lds[j] = 0.0f;
    float c = 0.0f;
    __syncthreads();

    const float* xwf = (const float*)xwv + (size_t)bb * SEQ * 512 + j;
    const unsigned short* xwb = (const unsigned short*)xwv + (size_t)bb * SEQ * 512 + j;

    float xw_cur = XWF32 ? xwf[0] : bf2f(xwb[0]);
    for (int t = 0; t < SEQ; ++t) {
        // prefetch next timestep's input projection (consumed next iter)
        float xw_next = 0.0f;
        if (t + 1 < SEQ)
            xw_next = XWF32 ? xwf[(size_t)(t + 1) * 512] : bf2f(xwb[(size_t)(t + 1) * 512]);

        float acc0 = 0.0f, acc1 = 0.0f;
        const float4* h4 = (const float4*)h_lds;
#pragma unroll
        for (int k4 = 0; k4 < 32; ++k4) {
            float4 hv = h4[k4]; // broadcast, conflict-free
            acc0 = fmaf(hv.x, u_reg[4 * k4 + 0], acc0);
            acc1 = fmaf(hv.y, u_reg[4 * k4 + 1], acc1);
            acc0 = fmaf(hv.z, u_reg[4 * k4 + 2], acc0);
            acc1 = fmaf(hv.w, u_reg[4 * k4 + 3], acc1);
        }
        float z = xw_cur + bj + (acc0 + acc1);
        g_lds[j] = fast_tanh(z);
        __syncthreads();
        if (j < UNITS) {
            float gi = g_lds[j];
            float gf = g_lds[128 + j];
            float gg = g_lds[256 + j];
            float go = g_lds[384 + j];
            c = fmaf(gf, c, gi * gg);
            h_lds[j] = go * fast_tanh(c);
        }
        __syncthreads();
        xw_cur = xw_next;
    }
    if (j < UNITS) out[bb * UNITS + j] = h_lds[j];
}

// ---------------------------------------------------------------------------
extern "C" void kernel_launch(void* const* d_in, const int* in_sizes, int n_in,
                              void* d_out, int out_size, void* d_ws, size_t ws_size,
                              hipStream_t stream) {
    const float* x = (const float*)d_in[0]; // [128,1024,512]
    const float* W = (const float*)d_in[1]; // [512,512]
    const float* U = (const float*)d_in[2]; // [128,512]
    const float* b = (const float*)d_in[3]; // [512]
    float* out = (float*)d_out;             // [128,128]

    char* ws = (char*)d_ws;
    const size_t WT_BYTES = (size_t)512 * 512 * 2; // 512 KB
    unsigned short* Wt = (unsigned short*)ws;
    void* xw = (void*)(ws + WT_BYTES);
    const size_t XW_F32_BYTES = (size_t)M_ROWS * 512 * 4; // 256 MB
    const bool f32path = (ws_size >= WT_BYTES + XW_F32_BYTES);

    k_wt<<<dim3(1024), dim3(256), 0, stream>>>(W, Wt);

    dim3 ggrid(4, 1024); // N-tiles x M-tiles
    if (f32path) {
        k_gemm<true><<<ggrid, dim3(256), 0, stream>>>(x, Wt, xw);
        k_scan<true><<<dim3(128), dim3(512), 0, stream>>>(xw, U, b, out);
    } else {
        k_gemm<false><<<ggrid, dim3(256), 0, stream>>>(x, Wt, xw);
        k_scan<false><<<dim3(128), dim3(512), 0, stream>>>(xw, U, b, out);
    }
}